// Round 1
// baseline (192.051 us; speedup 1.0000x reference)
//
#include <hip/hip_runtime.h>

// Problem constants (from reference)
#define VOCAB 50257
#define SEQ   2048
#define EMB   512
#define BATCH 8

constexpr int TILE = 32;

// Transpose W_emb (EMB, VOCAB) -> WT (VOCAB, EMB), LDS-tiled, padded to kill
// bank conflicts. Both global read and write are coalesced.
__global__ __launch_bounds__(256)
void transpose_k(const float* __restrict__ in, float* __restrict__ out) {
    __shared__ float tile[TILE][TILE + 1];
    const int v0 = blockIdx.x * TILE;   // vocab tile origin (input cols)
    const int e0 = blockIdx.y * TILE;   // emb tile origin (input rows)
    const int tx = threadIdx.x;         // 0..31
    const int ty = threadIdx.y;         // 0..7

    const int v = v0 + tx;
    if (v < VOCAB) {
#pragma unroll
        for (int j = 0; j < TILE; j += 8) {
            tile[ty + j][tx] = in[(size_t)(e0 + ty + j) * VOCAB + v];
        }
    }
    __syncthreads();

    const int e = e0 + tx;              // EMB=512 divides evenly, no bound needed
#pragma unroll
    for (int j = 0; j < TILE; j += 8) {
        const int vv = v0 + ty + j;
        if (vv < VOCAB) {
            out[(size_t)vv * EMB + e] = tile[tx][ty + j];
        }
    }
}

__device__ __forceinline__ float4 f4add(float4 a, float4 b) {
    return make_float4(a.x + b.x, a.y + b.y, a.z + b.z, a.w + b.w);
}

// Coalesced gather from the transposed table + fused positional add.
// One thread per float4 of output: idx in [0, B*S*EMB/4).
__global__ __launch_bounds__(256)
void gather_k(const int* __restrict__ tokens,
              const float4* __restrict__ WT,    // (VOCAB, EMB/4)
              const float4* __restrict__ Wpos,  // (SEQ, EMB/4)
              float4* __restrict__ out) {
    const int idx = blockIdx.x * blockDim.x + threadIdx.x;
    const int e4  = idx & (EMB / 4 - 1);    // 0..127
    const int ts  = idx >> 7;               // b*SEQ + s
    const int s   = ts & (SEQ - 1);
    const int t   = tokens[ts];
    const float4 emb = WT[(size_t)t * (EMB / 4) + e4];
    const float4 pos = Wpos[(size_t)s * (EMB / 4) + e4];
    out[idx] = f4add(emb, pos);
}

// Fallback if workspace can't hold the transposed table: direct strided gather.
__global__ __launch_bounds__(256)
void gather_direct_k(const int* __restrict__ tokens,
                     const float* __restrict__ W_emb,  // (EMB, VOCAB)
                     const float4* __restrict__ Wpos,
                     float4* __restrict__ out) {
    const int idx = blockIdx.x * blockDim.x + threadIdx.x;
    const int e4  = idx & (EMB / 4 - 1);
    const int ts  = idx >> 7;
    const int s   = ts & (SEQ - 1);
    const int t   = tokens[ts];
    const int e   = e4 * 4;
    float4 r;
    r.x = W_emb[(size_t)(e + 0) * VOCAB + t];
    r.y = W_emb[(size_t)(e + 1) * VOCAB + t];
    r.z = W_emb[(size_t)(e + 2) * VOCAB + t];
    r.w = W_emb[(size_t)(e + 3) * VOCAB + t];
    out[idx] = f4add(r, Wpos[(size_t)s * (EMB / 4) + e4]);
}

extern "C" void kernel_launch(void* const* d_in, const int* in_sizes, int n_in,
                              void* d_out, int out_size, void* d_ws, size_t ws_size,
                              hipStream_t stream) {
    const int*   tokens = (const int*)d_in[0];
    const float* W_emb  = (const float*)d_in[1];   // (EMB, VOCAB)
    const float* W_pos  = (const float*)d_in[2];   // (SEQ, EMB)
    float*       out    = (float*)d_out;           // (BATCH, SEQ, EMB)

    const size_t need = (size_t)VOCAB * EMB * sizeof(float);  // ~103 MB
    const int n_out4  = BATCH * SEQ * (EMB / 4);              // 2,097,152
    const int gblocks = n_out4 / 256;                          // 8192

    if (ws_size >= need) {
        float* WT = (float*)d_ws;
        dim3 tgrid((VOCAB + TILE - 1) / TILE, EMB / TILE);     // 1571 x 16
        transpose_k<<<tgrid, dim3(32, 8), 0, stream>>>(W_emb, WT);
        gather_k<<<gblocks, 256, 0, stream>>>(tokens, (const float4*)WT,
                                              (const float4*)W_pos, (float4*)out);
    } else {
        gather_direct_k<<<gblocks, 256, 0, stream>>>(tokens, W_emb,
                                                     (const float4*)W_pos, (float4*)out);
    }
}